// Round 6
// baseline (251.880 us; speedup 1.0000x reference)
//
#include <hip/hip_runtime.h>
#include <cstdint>

#define EPS 1e-5f
#define BB   8
#define CIN  384
#define HWs  4096
#define LT   32768
#define DD   128
#define NN   512
#define TOPK 81

typedef short short8 __attribute__((ext_vector_type(8)));   // 8 bf16 (4 VGPRs)
typedef float f32x4  __attribute__((ext_vector_type(4)));

__device__ __forceinline__ unsigned short f2bf(float x) {   // RNE, finite inputs
  unsigned u = __float_as_uint(x);
  u += 0x7fffu + ((u >> 16) & 1u);
  return (unsigned short)(u >> 16);
}
__device__ __forceinline__ float bf2f(unsigned u16) {
  return __uint_as_float(u16 << 16);
}
// write element (row rc in tile, k) of an operand as hi/lo bf16 in MFMA frag order.
// frag layout (HW-verified R1-R4): lane=((k>>3)&3)*16 + rc, j=k&7.
__device__ __forceinline__ void put_frag(unsigned short* buf, int tile, int rc, int k, float v) {
  int ks = k >> 5, g = (k >> 3) & 3, j = k & 7;
  int basehw = ((tile * 4 + ks) * 2) * 512 + (g * 16 + rc) * 8 + j;
  unsigned short hi = f2bf(v);
  buf[basehw] = hi;
  buf[basehw + 512] = f2bf(v - bf2f(hi));
}

// ---------------- K0: fused prep (DR layernorm + 3 weight-frag preps) ----------------
// blocks [0,128): DR rows (4 rows/block, 1 wave each)
// blocks [128,152): Win  [128,384] B-frags   (rt=idx&7, kb=idx>>3)
// blocks [152,160): semW [128,128] B-frags
// blocks [160,184): Wo   [384,128] B-frags
__global__ __launch_bounds__(256) void k_prep(const float* __restrict__ DR,
    const float* __restrict__ w2, const float* __restrict__ b2,
    const float* __restrict__ w1, const float* __restrict__ b1,
    const float* __restrict__ win, const float* __restrict__ sw,
    const float* __restrict__ wout,
    unsigned short* __restrict__ drwF, unsigned short* __restrict__ drlnF,
    float* __restrict__ t2, float* __restrict__ rcr,
    unsigned short* __restrict__ WinF, unsigned short* __restrict__ semWF,
    unsigned short* __restrict__ WoF) {
  int blk = blockIdx.x;
  int t = threadIdx.x;
  if (blk < 128) {
    // ---- DR part: wave w handles row n = blk*4 + w
    int w = t >> 6, lane = t & 63;
    int n = blk * 4 + w;
    const float* row = DR + n * DD;
    float x0 = row[lane], x1 = row[lane + 64];
    float s = x0 + x1, sq = x0 * x0 + x1 * x1;
    #pragma unroll
    for (int o = 32; o; o >>= 1) { s += __shfl_xor(s, o); sq += __shfl_xor(sq, o); }
    float m = s * (1.f / 128.f);
    float v = sq * (1.f / 128.f) - m * m;
    float inv = rsqrtf(v + EPS);
    float y0 = (x0 - m) * inv * w2[lane] + b2[lane];
    float y1 = (x1 - m) * inv * w2[lane + 64] + b2[lane + 64];
    int nt = n >> 4, cc = n & 15;
    put_frag(drwF, nt, cc, lane, y0 * w1[lane]);
    put_frag(drwF, nt, cc, lane + 64, y1 * w1[lane + 64]);
    int ks = n >> 5, gB = (n >> 3) & 3, j = n & 7;
    {
      int d = lane;
      unsigned short hi = f2bf(y0);
      int base = (((d >> 4) * 16 + ks) * 2) * 512 + (gB * 16 + (d & 15)) * 8 + j;
      drlnF[base] = hi;
      drlnF[base + 512] = f2bf(y0 - bf2f(hi));
    }
    {
      int d = lane + 64;
      unsigned short hi = f2bf(y1);
      int base = (((d >> 4) * 16 + ks) * 2) * 512 + (gB * 16 + (d & 15)) * 8 + j;
      drlnF[base] = hi;
      drlnF[base + 512] = f2bf(y1 - bf2f(hi));
    }
    float pt2 = y0 * b1[lane] + y1 * b1[lane + 64];
    float pss = y0 * y0 + y1 * y1;
    #pragma unroll
    for (int o = 32; o; o >>= 1) { pt2 += __shfl_xor(pt2, o); pss += __shfl_xor(pss, o); }
    if (lane == 0) { t2[n] = pt2; rcr[n] = rsqrtf(pss); }
    return;
  }
  // ---- weight B-frag prep
  const float* src;
  unsigned short* dst;
  int K, rt, kb = 0;
  if (blk < 152) {
    int idx = blk - 128;
    rt = idx & 7; kb = idx >> 3; src = win; dst = WinF; K = CIN;
  } else if (blk < 160) {
    rt = blk - 152; src = sw; dst = semWF; K = DD;
  } else {
    rt = blk - 160; src = wout; dst = WoF; K = DD;
  }
  int m = t >> 4, kg = t & 15;
  int k0 = kb * 128 + kg * 8;
  const float* s = src + (size_t)(rt * 16 + m) * K + k0;
  float4 f0 = *(const float4*)s;
  float4 f1 = *(const float4*)(s + 4);
  float vs[8] = {f0.x, f0.y, f0.z, f0.w, f1.x, f1.y, f1.z, f1.w};
  short8 hi, lo;
  #pragma unroll
  for (int j = 0; j < 8; ++j) {
    unsigned short h = f2bf(vs[j]);
    hi[j] = (short)h;
    lo[j] = (short)f2bf(vs[j] - bf2f(h));
  }
  int nkt = K >> 5;
  int ks = k0 >> 5, g = (k0 >> 3) & 3;
  short8* D8 = (short8*)dst;
  int base = ((rt * nkt + ks) * 2) * 64 + g * 16 + m;
  D8[base] = hi;
  D8[base + 64] = lo;
}

// ---------------- K1: conv_in (384 -> 128), split-bf16 MFMA ----------------
__global__ __launch_bounds__(256) void k_convin(const float* __restrict__ x,
    const unsigned short* __restrict__ WinF, const float* __restrict__ bias,
    unsigned short* __restrict__ xaF) {
  __shared__ float smem[64 * 132];
  int t = threadIdx.x;
  int w = t >> 6, lane = t & 63, m = lane & 15, g = lane >> 4;
  int l0 = blockIdx.x * 64;
  int b = l0 >> 12, hw0 = l0 & 4095;
  const float* xb = x + (size_t)b * CIN * HWs + hw0;
  const short8* B8 = (const short8*)WinF;
  f32x4 acc[4][2];
  #pragma unroll
  for (int lt = 0; lt < 4; ++lt)
    #pragma unroll
    for (int j2 = 0; j2 < 2; ++j2) acc[lt][j2] = (f32x4){0.f, 0.f, 0.f, 0.f};
  for (int ks = 0; ks < 12; ++ks) {
    short8 ah[4], al[4];
    const float* xc = xb + (size_t)(ks * 32 + g * 8) * HWs;
    #pragma unroll
    for (int lt = 0; lt < 4; ++lt) {
      const float* xcl = xc + lt * 16 + m;
      float v[8];
      #pragma unroll
      for (int j = 0; j < 8; ++j) v[j] = xcl[(size_t)j * HWs];
      #pragma unroll
      for (int j = 0; j < 8; ++j) {
        unsigned short h = f2bf(v[j]);
        ah[lt][j] = (short)h;
        al[lt][j] = (short)f2bf(v[j] - bf2f(h));
      }
    }
    #pragma unroll
    for (int j2 = 0; j2 < 2; ++j2) {
      int dt = w * 2 + j2;
      short8 bh = B8[((dt * 12 + ks) * 2 + 0) * 64 + lane];
      short8 bl = B8[((dt * 12 + ks) * 2 + 1) * 64 + lane];
      #pragma unroll
      for (int lt = 0; lt < 4; ++lt) {
        acc[lt][j2] = __builtin_amdgcn_mfma_f32_16x16x32_bf16(ah[lt], bh, acc[lt][j2], 0, 0, 0);
        acc[lt][j2] = __builtin_amdgcn_mfma_f32_16x16x32_bf16(ah[lt], bl, acc[lt][j2], 0, 0, 0);
        acc[lt][j2] = __builtin_amdgcn_mfma_f32_16x16x32_bf16(al[lt], bh, acc[lt][j2], 0, 0, 0);
      }
    }
  }
  float bia[2] = {bias[w * 32 + m], bias[w * 32 + 16 + m]};
  #pragma unroll
  for (int lt = 0; lt < 4; ++lt)
    #pragma unroll
    for (int j2 = 0; j2 < 2; ++j2)
      #pragma unroll
      for (int r = 0; r < 4; ++r)
        smem[(lt * 16 + g * 4 + r) * 132 + (w * 2 + j2) * 16 + m] = acc[lt][j2][r] + bia[j2];
  __syncthreads();
  short8* X8 = (short8*)xaF;
  #pragma unroll
  for (int it = 0; it < 4; ++it) {
    int idx = it * 256 + t;
    int l = idx & 63, dq = idx >> 6;
    const float* src = &smem[l * 132 + dq * 8];
    float4 f0 = *(const float4*)src;
    float4 f1 = *(const float4*)(src + 4);
    float vs[8] = {f0.x, f0.y, f0.z, f0.w, f1.x, f1.y, f1.z, f1.w};
    short8 hi, lo;
    #pragma unroll
    for (int j = 0; j < 8; ++j) {
      unsigned short h = f2bf(vs[j]);
      hi[j] = (short)h;
      lo[j] = (short)f2bf(vs[j] - bf2f(h));
    }
    int ltg = (l0 + l) >> 4;
    int idx8 = ((ltg * 4 + (dq >> 2)) * 2) * 64 + (dq & 3) * 16 + (l & 15);
    X8[idx8] = hi;
    X8[idx8 + 64] = lo;
  }
}

// ---------------- K2: sem conv (128->128) MFMA + LN1 + 2nd-LN fold ----------------
__global__ __launch_bounds__(256) void k_sem(const unsigned short* __restrict__ xaF,
    const unsigned short* __restrict__ semWF, const float* __restrict__ bias,
    const float* __restrict__ w1, const float* __restrict__ b1,
    unsigned short* __restrict__ ApF, float* __restrict__ rclv) {
  __shared__ float smem[64 * 132];
  __shared__ float sredS[64][4], sredQ[64][4];
  __shared__ float rowM[64], rowI[64];
  int t = threadIdx.x;
  int w = t >> 6, lane = t & 63, m = lane & 15, g = lane >> 4;
  int l0 = blockIdx.x * 64;
  int lt0 = l0 >> 4;
  const short8* A8 = (const short8*)xaF;
  const short8* B8 = (const short8*)semWF;
  f32x4 acc[4][2];
  #pragma unroll
  for (int lt = 0; lt < 4; ++lt)
    #pragma unroll
    for (int j2 = 0; j2 < 2; ++j2) acc[lt][j2] = (f32x4){0.f, 0.f, 0.f, 0.f};
  #pragma unroll
  for (int ks = 0; ks < 4; ++ks) {
    short8 ah[4], al[4];
    #pragma unroll
    for (int lt = 0; lt < 4; ++lt) {
      ah[lt] = A8[(((lt0 + lt) * 4 + ks) * 2 + 0) * 64 + lane];
      al[lt] = A8[(((lt0 + lt) * 4 + ks) * 2 + 1) * 64 + lane];
    }
    #pragma unroll
    for (int j2 = 0; j2 < 2; ++j2) {
      int dt = w * 2 + j2;
      short8 bh = B8[((dt * 4 + ks) * 2 + 0) * 64 + lane];
      short8 bl = B8[((dt * 4 + ks) * 2 + 1) * 64 + lane];
      #pragma unroll
      for (int lt = 0; lt < 4; ++lt) {
        acc[lt][j2] = __builtin_amdgcn_mfma_f32_16x16x32_bf16(ah[lt], bh, acc[lt][j2], 0, 0, 0);
        acc[lt][j2] = __builtin_amdgcn_mfma_f32_16x16x32_bf16(ah[lt], bl, acc[lt][j2], 0, 0, 0);
        acc[lt][j2] = __builtin_amdgcn_mfma_f32_16x16x32_bf16(al[lt], bh, acc[lt][j2], 0, 0, 0);
      }
    }
  }
  float bia[2] = {bias[w * 32 + m], bias[w * 32 + 16 + m]};
  #pragma unroll
  for (int lt = 0; lt < 4; ++lt)
    #pragma unroll
    for (int j2 = 0; j2 < 2; ++j2)
      #pragma unroll
      for (int r = 0; r < 4; ++r) acc[lt][j2][r] += bia[j2];
  float s1[4][4], q1[4][4];
  #pragma unroll
  for (int lt = 0; lt < 4; ++lt)
    #pragma unroll
    for (int r = 0; r < 4; ++r) {
      float a = acc[lt][0][r], b2v = acc[lt][1][r];
      s1[lt][r] = a + b2v;
      q1[lt][r] = a * a + b2v * b2v;
    }
  #pragma unroll
  for (int o = 1; o < 16; o <<= 1)
    #pragma unroll
    for (int lt = 0; lt < 4; ++lt)
      #pragma unroll
      for (int r = 0; r < 4; ++r) {
        s1[lt][r] += __shfl_xor(s1[lt][r], o);
        q1[lt][r] += __shfl_xor(q1[lt][r], o);
      }
  if (m == 0) {
    #pragma unroll
    for (int lt = 0; lt < 4; ++lt)
      #pragma unroll
      for (int r = 0; r < 4; ++r) {
        sredS[lt * 16 + g * 4 + r][w] = s1[lt][r];
        sredQ[lt * 16 + g * 4 + r][w] = q1[lt][r];
      }
  }
  __syncthreads();
  if (t < 64) {
    float S = sredS[t][0] + sredS[t][1] + sredS[t][2] + sredS[t][3];
    float Q = sredQ[t][0] + sredQ[t][1] + sredQ[t][2] + sredQ[t][3];
    float mu = S * (1.f / 128.f);
    float var = Q * (1.f / 128.f) - mu * mu;
    rowM[t] = mu;
    rowI[t] = rsqrtf(var + EPS);
  }
  __syncthreads();
  float w1v[2] = {w1[w * 32 + m], w1[w * 32 + 16 + m]};
  float b1v[2] = {b1[w * 32 + m], b1[w * 32 + 16 + m]};
  #pragma unroll
  for (int lt = 0; lt < 4; ++lt)
    #pragma unroll
    for (int r = 0; r < 4; ++r) {
      float mu = rowM[lt * 16 + g * 4 + r];
      float iv = rowI[lt * 16 + g * 4 + r];
      float y0 = (acc[lt][0][r] - mu) * iv * w1v[0] + b1v[0];
      float y1 = (acc[lt][1][r] - mu) * iv * w1v[1] + b1v[1];
      acc[lt][0][r] = y0; acc[lt][1][r] = y1;
      s1[lt][r] = y0 + y1;
      q1[lt][r] = y0 * y0 + y1 * y1;
    }
  #pragma unroll
  for (int o = 1; o < 16; o <<= 1)
    #pragma unroll
    for (int lt = 0; lt < 4; ++lt)
      #pragma unroll
      for (int r = 0; r < 4; ++r) {
        s1[lt][r] += __shfl_xor(s1[lt][r], o);
        q1[lt][r] += __shfl_xor(q1[lt][r], o);
      }
  if (m == 0) {
    #pragma unroll
    for (int lt = 0; lt < 4; ++lt)
      #pragma unroll
      for (int r = 0; r < 4; ++r) {
        sredS[lt * 16 + g * 4 + r][w] = s1[lt][r];
        sredQ[lt * 16 + g * 4 + r][w] = q1[lt][r];
      }
  }
  __syncthreads();
  if (t < 64) {
    float S = sredS[t][0] + sredS[t][1] + sredS[t][2] + sredS[t][3];
    float Q = sredQ[t][0] + sredQ[t][1] + sredQ[t][2] + sredQ[t][3];
    float m2 = S * (1.f / 128.f);
    float v2 = Q * (1.f / 128.f) - m2 * m2;
    float inv2 = rsqrtf(v2 + EPS);
    float rcl = rsqrtf(Q);
    rowM[t] = m2;
    rowI[t] = inv2 * rcl;
    rclv[l0 + t] = rcl;
  }
  __syncthreads();
  #pragma unroll
  for (int lt = 0; lt < 4; ++lt)
    #pragma unroll
    for (int r = 0; r < 4; ++r) {
      float m2 = rowM[lt * 16 + g * 4 + r];
      float sc = rowI[lt * 16 + g * 4 + r];
      smem[(lt * 16 + g * 4 + r) * 132 + w * 32 + m] = (acc[lt][0][r] - m2) * sc;
      smem[(lt * 16 + g * 4 + r) * 132 + w * 32 + 16 + m] = (acc[lt][1][r] - m2) * sc;
    }
  __syncthreads();
  short8* O8 = (short8*)ApF;
  #pragma unroll
  for (int it = 0; it < 4; ++it) {
    int idx = it * 256 + t;
    int l = idx & 63, dq = idx >> 6;
    const float* src = &smem[l * 132 + dq * 8];
    float4 f0 = *(const float4*)src;
    float4 f1 = *(const float4*)(src + 4);
    float vs[8] = {f0.x, f0.y, f0.z, f0.w, f1.x, f1.y, f1.z, f1.w};
    short8 hi, lo;
    #pragma unroll
    for (int j = 0; j < 8; ++j) {
      unsigned short h = f2bf(vs[j]);
      hi[j] = (short)h;
      lo[j] = (short)f2bf(vs[j] - bf2f(h));
    }
    int ltg = (l0 + l) >> 4;
    int idx8 = ((ltg * 4 + (dq >> 2)) * 2) * 64 + (dq & 3) * 16 + (l & 15);
    O8[idx8] = hi;
    O8[idx8 + 64] = lo;
  }
}

// ---------------- K3a: scores + softmax v2 (64 L-rows/block, split-bf16 MFMA) --------
// single-round flash softmax; pF assembled in LDS -> coalesced 16B stores
__global__ __launch_bounds__(256) void k_scores(const unsigned short* __restrict__ ApF,
    const unsigned short* __restrict__ drwF, const float* __restrict__ t2g,
    const float* __restrict__ rcrg, const float* __restrict__ rclg,
    unsigned short* __restrict__ pF, float* __restrict__ maxv) {
  __shared__ unsigned short pS[64 * 520];     // 64 rows x 512 cols bf16, pad 8
  __shared__ float sredM[64][4], sredS[64][4];
  int t = threadIdx.x;
  int w = t >> 6, lane = t & 63, c = lane & 15, g = lane >> 4;
  int l0 = blockIdx.x * 64;
  int lt0 = blockIdx.x * 4;
  const short8* A8 = (const short8*)ApF;
  const short8* B8 = (const short8*)drwF;
  f32x4 acc[4][8];
  #pragma unroll
  for (int lt = 0; lt < 4; ++lt)
    #pragma unroll
    for (int jn = 0; jn < 8; ++jn) acc[lt][jn] = (f32x4){0.f, 0.f, 0.f, 0.f};
  #pragma unroll
  for (int ks = 0; ks < 4; ++ks) {
    short8 ah[4], al[4];
    #pragma unroll
    for (int lt = 0; lt < 4; ++lt) {
      ah[lt] = A8[(((lt0 + lt) * 4 + ks) * 2 + 0) * 64 + lane];
      al[lt] = A8[(((lt0 + lt) * 4 + ks) * 2 + 1) * 64 + lane];
    }
    #pragma unroll
    for (int jn = 0; jn < 8; ++jn) {
      int nt = w * 8 + jn;
      short8 bh = B8[((nt * 4 + ks) * 2 + 0) * 64 + lane];
      short8 bl = B8[((nt * 4 + ks) * 2 + 1) * 64 + lane];
      #pragma unroll
      for (int lt = 0; lt < 4; ++lt) {
        acc[lt][jn] = __builtin_amdgcn_mfma_f32_16x16x32_bf16(ah[lt], bh, acc[lt][jn], 0, 0, 0);
        acc[lt][jn] = __builtin_amdgcn_mfma_f32_16x16x32_bf16(ah[lt], bl, acc[lt][jn], 0, 0, 0);
        acc[lt][jn] = __builtin_amdgcn_mfma_f32_16x16x32_bf16(al[lt], bh, acc[lt][jn], 0, 0, 0);
      }
    }
  }
  // ---- affine + per-wave softmax stats
  float rcrv[8], t2v[8];
  #pragma unroll
  for (int jn = 0; jn < 8; ++jn) {
    int n = w * 128 + jn * 16 + c;
    rcrv[jn] = rcrg[n]; t2v[jn] = t2g[n];
  }
  float rclr[4][4];
  #pragma unroll
  for (int lt = 0; lt < 4; ++lt)
    #pragma unroll
    for (int r = 0; r < 4; ++r)
      rclr[lt][r] = rclg[l0 + lt * 16 + g * 4 + r];
  float M[4][4], S[4][4];
  #pragma unroll
  for (int lt = 0; lt < 4; ++lt)
    #pragma unroll
    for (int r = 0; r < 4; ++r) M[lt][r] = -1e30f;
  #pragma unroll
  for (int lt = 0; lt < 4; ++lt)
    #pragma unroll
    for (int jn = 0; jn < 8; ++jn) {
      f32x4 a = acc[lt][jn];
      #pragma unroll
      for (int r = 0; r < 4; ++r) {
        float s = rcrv[jn] * (a[r] + rclr[lt][r] * t2v[jn]);
        a[r] = s;
        M[lt][r] = fmaxf(M[lt][r], s);
      }
      acc[lt][jn] = a;
    }
  #pragma unroll
  for (int o = 1; o < 16; o <<= 1)
    #pragma unroll
    for (int lt = 0; lt < 4; ++lt)
      #pragma unroll
      for (int r = 0; r < 4; ++r)
        M[lt][r] = fmaxf(M[lt][r], __shfl_xor(M[lt][r], o));
  #pragma unroll
  for (int lt = 0; lt < 4; ++lt)
    #pragma unroll
    for (int r = 0; r < 4; ++r) S[lt][r] = 0.f;
  #pragma unroll
  for (int lt = 0; lt < 4; ++lt)
    #pragma unroll
    for (int jn = 0; jn < 8; ++jn) {
      f32x4 a = acc[lt][jn];
      #pragma unroll
      for (int r = 0; r < 4; ++r) {
        float e = expf(a[r] - M[lt][r]);
        a[r] = e;
        S[lt][r] += e;
      }
      acc[lt][jn] = a;
    }
  #pragma unroll
  for (int o = 1; o < 16; o <<= 1)
    #pragma unroll
    for (int lt = 0; lt < 4; ++lt)
      #pragma unroll
      for (int r = 0; r < 4; ++r)
        S[lt][r] += __shfl_xor(S[lt][r], o);
  if (c == 0) {
    #pragma unroll
    for (int lt = 0; lt < 4; ++lt)
      #pragma unroll
      for (int r = 0; r < 4; ++r) {
        sredM[lt * 16 + g * 4 + r][w] = M[lt][r];
        sredS[lt * 16 + g * 4 + r][w] = S[lt][r];
      }
  }
  __syncthreads();
  // global combine (exact rescale): p = e * exp(M_w - Mg) / Sg
  #pragma unroll
  for (int lt = 0; lt < 4; ++lt) {
    #pragma unroll
    for (int r = 0; r < 4; ++r) {
      int row = lt * 16 + g * 4 + r;
      float m0 = sredM[row][0], m1 = sredM[row][1], m2 = sredM[row][2], m3 = sredM[row][3];
      float Mg = fmaxf(fmaxf(m0, m1), fmaxf(m2, m3));
      float Sg = sredS[row][0] * expf(m0 - Mg) + sredS[row][1] * expf(m1 - Mg)
               + sredS[row][2] * expf(m2 - Mg) + sredS[row][3] * expf(m3 - Mg);
      float F = expf(M[lt][r] - Mg) / Sg;
      #pragma unroll
      for (int jn = 0; jn < 8; ++jn)
        pS[row * 520 + w * 128 + jn * 16 + c] = f2bf(acc[lt][jn][r] * F);
    }
  }
  if (t < 64) {
    float m0 = sredM[t][0], m1 = sredM[t][1], m2 = sredM[t][2], m3 = sredM[t][3];
    float Mg = fmaxf(fmaxf(m0, m1), fmaxf(m2, m3));
    float Sg = sredS[t][0] * expf(m0 - Mg) + sredS[t][1] * expf(m1 - Mg)
             + sredS[t][2] * expf(m2 - Mg) + sredS[t][3] * expf(m3 - Mg);
    maxv[l0 + t] = 1.f / Sg;
  }
  __syncthreads();
  // coalesced frag-pack store: O8[lt0*1024 + fl], fl = t + i*256
  short8* O8 = (short8*)pF + lt0 * 1024;
  #pragma unroll
  for (int i = 0; i < 16; ++i) {
    int fl = t + i * 256;
    int lt = fl >> 10, ks = (fl >> 6) & 15, gB = (fl >> 4) & 3, mrow = fl & 15;
    O8[fl] = *(const short8*)&pS[(lt * 16 + mrow) * 520 + ks * 32 + gB * 8];
  }
}

// ---------------- K3b: degrad (pF @ drlnF) + conv_out (128->384), all MFMA ----------------
__global__ __launch_bounds__(256) void k_deg(const unsigned short* __restrict__ pF,
    const unsigned short* __restrict__ drlnF, const unsigned short* __restrict__ WoF,
    const float* __restrict__ bo, float* __restrict__ out_img) {
  __shared__ float smem[64 * 132];
  int t = threadIdx.x;
  int w = t >> 6, lane = t & 63, c = lane & 15, g = lane >> 4;
  int l0 = blockIdx.x * 64;
  int lt0 = l0 >> 4;
  const short8* P8 = (const short8*)pF;
  const short8* D8 = (const short8*)drlnF;
  const short8* W8 = (const short8*)WoF;
  f32x4 acc[4][2];
  #pragma unroll
  for (int lt = 0; lt < 4; ++lt)
    #pragma unroll
    for (int j2 = 0; j2 < 2; ++j2) acc[lt][j2] = (f32x4){0.f, 0.f, 0.f, 0.f};
  for (int ks = 0; ks < 16; ++ks) {
    short8 a0 = P8[((lt0 + 0) * 16 + ks) * 64 + lane];
    short8 a1 = P8[((lt0 + 1) * 16 + ks) * 64 + lane];
    short8 a2 = P8[((lt0 + 2) * 16 + ks) * 64 + lane];
    short8 a3 = P8[((lt0 + 3) * 16 + ks) * 64 + lane];
    #pragma unroll
    for (int j2 = 0; j2 < 2; ++j2) {
      int dt = w * 2 + j2;
      short8 bh = D8[((dt * 16 + ks) * 2 + 0) * 64 + lane];
      short8 bl = D8[((dt * 16 + ks) * 2 + 1) * 64 + lane];
      acc[0][j2] = __builtin_amdgcn_mfma_f32_16x16x32_bf16(a0, bh, acc[0][j2], 0, 0, 0);
      acc[0][j2] = __builtin_amdgcn_mfma_f32_16x16x32_bf16(a0, bl, acc[0][j2], 0, 0, 0);
      acc[1][j2] = __builtin_amdgcn_mfma_f32_16x16x32_bf16(a1, bh, acc[1][j2], 0, 0, 0);
      acc[1][j2] = __builtin_amdgcn_mfma_f32_16x16x32_bf16(a1, bl, acc[1][j2], 0, 0, 0);
      acc[2][j2] = __builtin_amdgcn_mfma_f32_16x16x32_bf16(a2, bh, acc[2][j2], 0, 0, 0);
      acc[2][j2] = __builtin_amdgcn_mfma_f32_16x16x32_bf16(a2, bl, acc[2][j2], 0, 0, 0);
      acc[3][j2] = __builtin_amdgcn_mfma_f32_16x16x32_bf16(a3, bh, acc[3][j2], 0, 0, 0);
      acc[3][j2] = __builtin_amdgcn_mfma_f32_16x16x32_bf16(a3, bl, acc[3][j2], 0, 0, 0);
    }
  }
  #pragma unroll
  for (int lt = 0; lt < 4; ++lt)
    #pragma unroll
    for (int j2 = 0; j2 < 2; ++j2)
      #pragma unroll
      for (int r = 0; r < 4; ++r)
        smem[(lt * 16 + g * 4 + r) * 132 + w * 32 + j2 * 16 + c] = acc[lt][j2][r];
  __syncthreads();
  f32x4 acc2[4][6];
  #pragma unroll
  for (int lt = 0; lt < 4; ++lt)
    #pragma unroll
    for (int ot = 0; ot < 6; ++ot) acc2[lt][ot] = (f32x4){0.f, 0.f, 0.f, 0.f};
  #pragma unroll
  for (int ks2 = 0; ks2 < 4; ++ks2) {
    short8 dh[4];
    #pragma unroll
    for (int lt = 0; lt < 4; ++lt) {
      const float* src = &smem[(lt * 16 + c) * 132 + ks2 * 32 + g * 8];
      float4 f0 = *(const float4*)src;
      float4 f1 = *(const float4*)(src + 4);
      float vs[8] = {f0.x, f0.y, f0.z, f0.w, f1.x, f1.y, f1.z, f1.w};
      #pragma unroll
      for (int j = 0; j < 8; ++j) dh[lt][j] = (short)f2bf(vs[j]);
    }
    #pragma unroll
    for (int ot = 0; ot < 6; ++ot) {
      int otg = w * 6 + ot;
      short8 wh = W8[((otg * 4 + ks2) * 2 + 0) * 64 + lane];
      short8 wl = W8[((otg * 4 + ks2) * 2 + 1) * 64 + lane];
      #pragma unroll
      for (int lt = 0; lt < 4; ++lt) {
        acc2[lt][ot] = __builtin_amdgcn_mfma_f32_16x16x32_bf16(dh[lt], wh, acc2[lt][ot], 0, 0, 0);
        acc2[lt][ot] = __builtin_amdgcn_mfma_f32_16x16x32_bf16(dh[lt], wl, acc2[lt][ot], 0, 0, 0);
      }
    }
  }
  __syncthreads();
  int b = l0 >> 12, hw0 = l0 & 4095;
  float* ob = out_img + (size_t)b * CIN * HWs + hw0;
  float bov[6];
  #pragma unroll
  for (int ot = 0; ot < 6; ++ot) bov[ot] = bo[w * 96 + ot * 16 + c];
  for (int ot = 0; ot < 6; ++ot) {
    #pragma unroll
    for (int lt = 0; lt < 4; ++lt)
      #pragma unroll
      for (int r = 0; r < 4; ++r)
        smem[(lt * 16 + g * 4 + r) * 65 + w * 16 + c] = acc2[lt][ot][r] + bov[ot];
    __syncthreads();
    #pragma unroll
    for (int i = 0; i < 16; ++i) {
      int idx = t + i * 256;
      int o_l = idx >> 6, ll = idx & 63;
      int o = (o_l >> 4) * 96 + ot * 16 + (o_l & 15);
      ob[(size_t)o * HWs + ll] = smem[ll * 65 + o_l];
    }
    __syncthreads();
  }
}

// ---------------- K5: fused mask + top-81 radix-select ----------------
__global__ __launch_bounds__(256) void k_mtk(const float* __restrict__ maxv,
                                             float* __restrict__ outm,
                                             int* __restrict__ tix) {
  __shared__ unsigned int hist[4][256];
  __shared__ unsigned long long slist[TOPK];
  __shared__ unsigned long long bc_prefix;
  __shared__ int bc_need, scount;
  __shared__ float smn[4], smx[4];
  int b = blockIdx.x, t = threadIdx.x;
  int w = t >> 6;
  float val[16];
  unsigned long long key[16];
  float mn = 1e30f, mx = -1e30f;
  #pragma unroll
  for (int j = 0; j < 16; ++j) {
    int idx = t + j * 256;
    float x = maxv[b * HWs + idx];
    val[j] = x;
    float cc = x * x * x;
    mn = fminf(mn, cc); mx = fmaxf(mx, cc);
    key[j] = ((unsigned long long)__float_as_uint(x) << 12) | (unsigned)(4095 - idx);
  }
  #pragma unroll
  for (int o = 32; o; o >>= 1) { mn = fminf(mn, __shfl_xor(mn, o)); mx = fmaxf(mx, __shfl_xor(mx, o)); }
  if ((t & 63) == 0) { smn[w] = mn; smx[w] = mx; }
  if (t == 0) { bc_prefix = 0ull; bc_need = TOPK; scount = 0; }
  __syncthreads();
  mn = fminf(fminf(smn[0], smn[1]), fminf(smn[2], smn[3]));
  mx = fmaxf(fmaxf(smx[0], smx[1]), fmaxf(smx[2], smx[3]));
  float sc = 1.f / (mx - mn);
  #pragma unroll
  for (int j = 0; j < 16; ++j) {
    float cc = val[j] * val[j] * val[j];
    outm[b * HWs + t + j * 256] = 1.f - (cc - mn) * sc;
  }
  // ---- radix select
  for (int r = 0; r < 6; ++r) {
    int shift = 40 - 8 * r;
    unsigned int* hflat = (unsigned int*)hist;
    hflat[t] = 0; hflat[t + 256] = 0; hflat[t + 512] = 0; hflat[t + 768] = 0;
    __syncthreads();
    unsigned long long prefix = bc_prefix;
    int bins[16];
    #pragma unroll
    for (int j = 0; j < 16; ++j)
      bins[j] = ((key[j] >> (shift + 8)) == prefix) ? (int)((key[j] >> shift) & 255) : -1;
    #pragma unroll
    for (int j = 0; j < 16; ++j) {
      if (bins[j] >= 0) {
        int cnt = 1;
        #pragma unroll
        for (int j2 = j + 1; j2 < 16; ++j2)
          if (bins[j2] == bins[j]) { bins[j2] = -1; ++cnt; }
        atomicAdd(&hist[w][bins[j]], (unsigned)cnt);
      }
    }
    __syncthreads();
    if (t < 64) {
      int cb[4], s = 0;
      #pragma unroll
      for (int j = 0; j < 4; ++j) {
        int bin = 255 - (t * 4 + j);
        cb[j] = (int)(hist[0][bin] + hist[1][bin] + hist[2][bin] + hist[3][bin]);
        s += cb[j];
      }
      int P = s;
      #pragma unroll
      for (int o = 1; o < 64; o <<= 1) {
        int u = __shfl_up(P, o);
        if (t >= o) P += u;
      }
      int need = bc_need;
      unsigned long long mask = __ballot(P >= need);
      int first = __ffsll((long long)mask) - 1;
      if (t == first) {
        int acc = P - s;
        #pragma unroll
        for (int j = 0; j < 4; ++j) {
          if (acc + cb[j] >= need) {
            bc_prefix = (prefix << 8) | (unsigned)(255 - (t * 4 + j));
            bc_need = need - acc;
            break;
          }
          acc += cb[j];
        }
      }
    }
    __syncthreads();
  }
  unsigned long long K81 = bc_prefix;
  #pragma unroll
  for (int j = 0; j < 16; ++j)
    if (key[j] >= K81) {
      int pos = atomicAdd(&scount, 1);
      slist[pos] = key[j];
    }
  __syncthreads();
  if (t < TOPK) {
    unsigned long long mine = slist[t];
    int rank = 0;
    for (int i = 0; i < TOPK; ++i) rank += (slist[i] > mine) ? 1 : 0;
    tix[b * TOPK + rank] = 4095 - (int)(mine & 0xFFFull);
  }
}

// ---------------- K6: gather ----------------
__global__ __launch_bounds__(128) void k_gather(const unsigned short* __restrict__ pF,
    const int* __restrict__ tix, float* __restrict__ outr) {
  int gB_ = blockIdx.x;
  int k = gB_ % TOPK;
  int bb = gB_ / TOPK;
  int b2 = bb & 7, b = bb >> 3;
  int l = b * HWs + tix[b2 * TOPK + k];
  int lt = l >> 4, mrow = l & 15;
  int t = threadIdx.x;
  int ks = t >> 3, gq = (t >> 1) & 3, j0 = (t & 1) * 4;
  int base = ((lt * 16 + ks) * 64 + gq * 16 + mrow) * 8 + j0;
  const unsigned* src = (const unsigned*)(pF + base);
  unsigned u0 = src[0], u1 = src[1];
  float4 v = {bf2f(u0 & 0xffffu), bf2f(u0 >> 16), bf2f(u1 & 0xffffu), bf2f(u1 >> 16)};
  *(float4*)(outr + (size_t)gB_ * NN + t * 4) = v;
}

extern "C" void kernel_launch(void* const* d_in, const int* in_sizes, int n_in,
                              void* d_out, int out_size, void* d_ws, size_t ws_size,
                              hipStream_t stream) {
  const float* x    = (const float*)d_in[0];
  const float* DR   = (const float*)d_in[1];
  const float* win  = (const float*)d_in[2];
  const float* bin  = (const float*)d_in[3];
  const float* sw   = (const float*)d_in[4];
  const float* sb   = (const float*)d_in[5];
  const float* n1w  = (const float*)d_in[6];
  const float* n1b  = (const float*)d_in[7];
  const float* n2w  = (const float*)d_in[8];
  const float* n2b  = (const float*)d_in[9];
  const float* wout = (const float*)d_in[10];
  const float* bout = (const float*)d_in[11];
  float* out = (float*)d_out;
  float* W = (float*)d_ws;

  // workspace layout (float offsets), ~68.4 MB
  unsigned short* drwF  = (unsigned short*)(W);            // 65536 f
  float* t2   = W + 65536;                                 // 512
  float* rcr  = W + 66048;                                 // 512
  float* rclv = W + 66560;                                 // 32768
  float* maxv = W + 99328;                                 // 32768
  unsigned short* drlnF = (unsigned short*)(W + 132096);   // 65536 f
  unsigned short* WoF   = (unsigned short*)(W + 197632);   // 49152 f
  unsigned short* WinF  = (unsigned short*)(W + 246784);   // 49152 f
  unsigned short* semWF = (unsigned short*)(W + 295936);   // 16384 f
  unsigned short* ApF   = (unsigned short*)(W + 312320);   // 4194304 f
  unsigned short* xaF   = (unsigned short*)(W + 4506624);  // 4194304 f (dead after k_sem)
  unsigned short* pF    = (unsigned short*)(W + 4506624);  // 8388608 f (aliases xaF)
  int*   tix  = (int*)(W + 12895232);                      // 648 ints

  float* out_mask = out;
  float* out_img  = out + 32768;
  float* out_res  = out + 32768 + 12582912;

  k_prep  <<<184,  256, 0, stream>>>(DR, n2w, n2b, n1w, n1b, win, sw, wout,
                                     drwF, drlnF, t2, rcr, WinF, semWF, WoF);
  k_convin<<<512,  256, 0, stream>>>(x, WinF, bin, xaF);
  k_sem   <<<512,  256, 0, stream>>>(xaF, semWF, sb, n1w, n1b, ApF, rclv);
  k_scores<<<512,  256, 0, stream>>>(ApF, drwF, t2, rcr, rclv, pF, maxv);
  k_deg   <<<512,  256, 0, stream>>>(pF, drlnF, WoF, bout, out_img);
  k_mtk   <<<BB,   256, 0, stream>>>(maxv, out_mask, tix);
  k_gather<<<BB * BB * TOPK, 128, 0, stream>>>(pF, tix, out_res);
}